// Round 4
// baseline (154.472 us; speedup 1.0000x reference)
//
#include <hip/hip_runtime.h>
#include <hip/hip_bf16.h>
#include <stdint.h>

#define M_ROWS 8192
#define K_IN   2048
#define KB4    (K_IN / 2)          // packed fp4 bytes per row = 1024
#define N_OUT  2048

typedef int   v4i    __attribute__((ext_vector_type(4)));
typedef int   v8i    __attribute__((ext_vector_type(8)));
typedef float f32x4  __attribute__((ext_vector_type(4)));
typedef float f32x16 __attribute__((ext_vector_type(16)));

// ---------------------------------------------------------------------------
// async global->LDS, 16B per lane. LDS dest = wave-uniform base + lane*16.
__device__ __forceinline__ void load_lds16(const void* g, void* l) {
    __builtin_amdgcn_global_load_lds(
        (const __attribute__((address_space(1))) uint32_t*)g,
        (__attribute__((address_space(3))) uint32_t*)l,
        16, 0, 0);
}

// Widen a 4-reg fp4 fragment to the 8-reg f8f6f4 operand shape with UNDEF
// upper half (fp4 format cbsz/blgp=4 reads only regs [0:3]).
__device__ __forceinline__ v8i pad8(v4i lo) {
    return __builtin_shufflevector(lo, lo, 0, 1, 2, 3, -1, -1, -1, -1);
}

// fp4 e2m1 RNE quantization of v. Levels: 0,0.5,1,1.5,2,3,4,6.
__device__ __forceinline__ uint32_t fp4_e2m1(float v) {
    float m = fabsf(v);
    uint32_t s = (v < 0.f) ? 0x8u : 0x0u;
    uint32_t c;
    if      (m < 0.25f) c = 0;
    else if (m < 0.75f) c = 1;
    else if (m < 1.25f) c = 2;
    else if (m < 1.75f) c = 3;
    else if (m < 2.50f) c = 4;
    else if (m < 3.50f) c = 5;
    else if (m < 5.00f) c = 6;
    else                c = 7;
    return (c == 0) ? 0u : (s | c);
}

// ---------------------------------------------------------------------------
// Quantization. One wave per row, no barriers.
// Waves [0, M_ROWS): input rows -> per-row absmax + sign(x) as packed fp4,
//   ROW-MAJOR Aq[m][KB4]. R8: lane owns 32 contiguous elems -> ONE coalesced
//   uint4 store (1 KB/wave-instr) instead of 8 uint16 stores (128 B/instr).
//   Mirrors the verified weight path; identical Aq bytes.
// Waves [M_ROWS, +N_OUT): weight rows -> e2m1(sign(w)/gamma) written
//   CHUNK-TRANSPOSED: Wqt[c][n][16B], c = k/32 (lane L handles chunk L).
__global__ __launch_bounds__(256) void quant_rows(
    const float* __restrict__ in, const float* __restrict__ w,
    const float* __restrict__ gamma,
    uint8_t* __restrict__ aq, uint8_t* __restrict__ wqt,
    float* __restrict__ scale)
{
    const int lane = threadIdx.x & 63;
    const int wv   = threadIdx.x >> 6;
    const int gw   = blockIdx.x * 4 + wv;          // global wave id = row id

    if (gw < M_ROWS) {
        // lane covers elems [lane*32, lane*32+32) of row gw
        const float4* rp = (const float4*)(in + (size_t)gw * K_IN + lane * 32);
        float m = 0.f;
        uint32_t pk[4] = {0, 0, 0, 0};
        #pragma unroll
        for (int j = 0; j < 8; j++) {
            float4 x = rp[j];
            float xs[4] = {x.x, x.y, x.z, x.w};
            #pragma unroll
            for (int c = 0; c < 4; c++) {
                m = fmaxf(m, fabsf(xs[c]));
                int e = j * 4 + c;                 // elem index within chunk
                uint32_t n = (xs[c] > 0.f) ? 0x2u : ((xs[c] < 0.f) ? 0xAu : 0u);
                pk[e >> 3] |= n << ((e & 7) * 4);
            }
        }
        uint4 v; v.x = pk[0]; v.y = pk[1]; v.z = pk[2]; v.w = pk[3];
        *(uint4*)(aq + (size_t)gw * KB4 + lane * 16) = v;
        #pragma unroll
        for (int off = 32; off > 0; off >>= 1) m = fmaxf(m, __shfl_down(m, off));
        if (lane == 0) scale[gw] = m;
    } else {
        const int r = gw - M_ROWS;
        // lane L quantizes elems [L*32, L*32+32) of row r -> one 16B chunk
        const float4* rp = (const float4*)(w + (size_t)r * K_IN + lane * 32);
        const float4* gp = (const float4*)(gamma + lane * 32);
        uint32_t pk[4] = {0, 0, 0, 0};
        #pragma unroll
        for (int j = 0; j < 8; j++) {
            float4 x = rp[j];
            float4 g = gp[j];
            float xs[4] = {x.x, x.y, x.z, x.w};
            float gs[4] = {g.x, g.y, g.z, g.w};
            #pragma unroll
            for (int c = 0; c < 4; c++) {
                int e = j * 4 + c;                 // elem index within chunk
                float s = (xs[c] > 0.f) ? 1.f : ((xs[c] < 0.f) ? -1.f : 0.f);
                pk[e >> 3] |= fp4_e2m1(s / gs[c]) << ((e & 7) * 4);
            }
        }
        uint4 v; v.x = pk[0]; v.y = pk[1]; v.z = pk[2]; v.w = pk[3];
        *(uint4*)(wqt + ((size_t)lane * N_OUT + r) * 16) = v;
    }
}

// ---------------------------------------------------------------------------
// MX-fp4 MFMA GEMM, B DIRECT FROM GLOBAL (L2/L3-resident, chunk-transposed).
// C[m,n] = sum_k Aq[m,k]*Wqt[k,n]. 128x128 block tile, BK=256 elems
// (128 B of A per row per iter), 8 K-iters.
//
// R8 (this round): 32x32x64 MFMA shape (was 16x16x128). Same 16 B/lane
// fragment K-coverage -> Wqt layout, LDS layout, XOR swizzle unchanged;
// lane decomposition becomes fr=lane&31 (row/col), g=lane>>5 (16B k-chunk).
// Halves MFMA instr count (16 per wave per k-iter at 2x FLOP) and uses the
// faster measured rate (9099 vs 7228 TF). 4 waves own 64x64 each via 2x2
// grid of 32x32 MFMAs, 4 k-steps (64 elems) per k-iter.
//
// Session ledger:
//   R3: (256,4) caps VGPR at 64, spills acc -> 2.5x slower. Keep (256,2).
//   R4: register-staged LDS dbuf loses on LDS-port pressure.
//   R5: T3/T4 counted-vmcnt pipeline -> NULL (TLP hides drain). Reverted.
//   R6: T1 XCD-aware remap -> NULL (data L3-fit; m160). Reverted.
//   R7: undef-upper pad8 -> NULL (compiler already optimal). Kept, harmless.
#define BM   128
#define BN   128
#define BKBY 128   /* bytes of packed fp4 A per row per iter = 256 elems */

__global__ __launch_bounds__(256, 2) void gemm_q(
    const uint8_t* __restrict__ Aq,
    const uint8_t* __restrict__ Wqt,
    const float* __restrict__ scale,
    const float* __restrict__ bias,
    const float* __restrict__ beta,
    float* __restrict__ out)
{
    __shared__ uint8_t As[BM * BKBY];   // 16 KB

    const int tid  = threadIdx.x;
    const int lane = tid & 63;
    const int wave = tid >> 6;

    const int row0 = blockIdx.x * BM;
    const int col0 = blockIdx.y * BN;

    const int wm = (wave >> 1) * 64;
    const int wn = (wave & 1)  * 64;

    // A staging: thread t (issue i) covers row i*32 + (t>>3), phys chunk t&7
    const int st_row = tid >> 3;                 // 0..31
    const int st_pc  = tid & 7;                  // physical 16B chunk
    const int st_gc  = st_pc ^ (st_row & 7);     // swizzled source chunk

    const uint8_t* gA = Aq + (size_t)(row0 + st_row) * KB4 + st_gc * 16;
    uint8_t* lA = &As[st_row * BKBY + st_pc * 16];

    f32x16 acc[2][2];
    #pragma unroll
    for (int i = 0; i < 2; i++) {
        #pragma unroll
        for (int j = 0; j < 2; j++) acc[i][j] = (f32x16)(0.f);
    }

    const int fr = lane & 31;            // fragment row (m) / col (n)
    const int g  = lane >> 5;            // k-half-chunk (32 elems = 16 B)

    // B: plane stride = one k-chunk (32 elems) of all N columns
    const size_t PS = (size_t)N_OUT * 16;        // 32 KB
    const uint8_t* gBt = Wqt + (size_t)(col0 + wn + fr) * 16 + (size_t)g * PS;

    for (int kb = 0; kb < KB4; kb += BKBY) {
        #pragma unroll
        for (int i = 0; i < 4; i++)
            load_lds16(gA + (size_t)(i * 32) * KB4 + kb, lA + i * 32 * BKBY);

        const uint8_t* bp = gBt + (size_t)(kb >> 4) * PS;
        v4i b01[2][2];
        #pragma unroll
        for (int ks = 0; ks < 2; ks++)           // ks=0,1 frags: overlap DMA drain
            #pragma unroll
            for (int ni = 0; ni < 2; ni++)
                b01[ks][ni] = *(const v4i*)(bp + (size_t)(ks * 2) * PS + ni * 512);

        __syncthreads();

        v4i b23[2][2];
        #pragma unroll
        for (int ks = 0; ks < 2; ks++)           // ks=2,3 frags: overlap early MFMAs
            #pragma unroll
            for (int ni = 0; ni < 2; ni++)
                b23[ks][ni] = *(const v4i*)(bp + (size_t)((ks + 2) * 2) * PS + ni * 512);

        #pragma unroll
        for (int ks = 0; ks < 4; ks++) {
            // A chunk for this k-step: logical chunk ks*2+g, XOR-swizzled per row
            const int offA = ((ks * 2 + g) ^ (fr & 7)) << 4;
            v8i a[2];
            #pragma unroll
            for (int mi = 0; mi < 2; mi++) {
                v4i lo = *(const v4i*)(&As[(wm + mi * 32 + fr) * BKBY] + offA);
                a[mi] = pad8(lo);
            }
            #pragma unroll
            for (int mi = 0; mi < 2; mi++) {
                #pragma unroll
                for (int ni = 0; ni < 2; ni++) {
                    v4i lb = (ks < 2) ? b01[ks][ni] : b23[ks - 2][ni];
                    acc[mi][ni] = __builtin_amdgcn_mfma_scale_f32_32x32x64_f8f6f4(
                        a[mi], pad8(lb), acc[mi][ni],
                        4 /*cbsz: A=fp4 e2m1*/, 4 /*blgp: B=fp4 e2m1*/,
                        0, 0x7F7F7F7F,   /* A scales = 1.0 */
                        0, 0x7F7F7F7F);  /* B scales = 1.0 */
                }
            }
        }
        __syncthreads();
    }

    // epilogue: 32x32 C/D layout: col=lane&31, row=(reg&3)+8*(reg>>2)+4*(lane>>5)
    const int ecol = fr;                 // lane & 31
    float bi[2], be[2];
    #pragma unroll
    for (int ni = 0; ni < 2; ni++) {
        int col = col0 + wn + ni * 32 + ecol;
        bi[ni] = bias[col];
        be[ni] = beta[col];
    }
    #pragma unroll
    for (int mi = 0; mi < 2; mi++) {
        const int rbase = row0 + wm + mi * 32 + 4 * g;
        float sc[16];
        #pragma unroll
        for (int r = 0; r < 16; r++)
            sc[r] = scale[rbase + (r & 3) + 8 * (r >> 2)];
        #pragma unroll
        for (int ni = 0; ni < 2; ni++) {
            int col = col0 + wn + ni * 32 + ecol;
            #pragma unroll
            for (int r = 0; r < 16; r++) {
                int row = rbase + (r & 3) + 8 * (r >> 2);
                out[(size_t)row * N_OUT + col] =
                    (acc[mi][ni][r] * sc[r] + bi[ni]) * be[ni];
            }
        }
    }
}

// ---------------------------------------------------------------------------
// Fallback (no workspace): correct but slow.
__global__ __launch_bounds__(256) void fallback_kernel(
    const float* __restrict__ in, const float* __restrict__ w,
    const float* __restrict__ bias, const float* __restrict__ gamma,
    const float* __restrict__ beta, float* __restrict__ out)
{
    __shared__ float s_sign[K_IN];
    __shared__ float sred[4];
    const int row = blockIdx.x;
    const int tid = threadIdx.x;
    float m = 0.f;
    for (int k = tid; k < K_IN; k += 256) {
        float x = in[(size_t)row * K_IN + k];
        m = fmaxf(m, fabsf(x));
        float s = (x > 0.f) ? 1.f : ((x < 0.f) ? -1.f : 0.f);
        s_sign[k] = s / gamma[k];
    }
    #pragma unroll
    for (int off = 32; off > 0; off >>= 1) m = fmaxf(m, __shfl_down(m, off));
    if ((tid & 63) == 0) sred[tid >> 6] = m;
    __syncthreads();
    float qs = fmaxf(fmaxf(sred[0], sred[1]), fmaxf(sred[2], sred[3]));
    for (int o = tid; o < N_OUT; o += 256) {
        const float* wr = w + (size_t)o * K_IN;
        float acc2 = 0.f;
        for (int k = 0; k < K_IN; k++) {
            float wv = wr[k];
            float ws_ = (wv > 0.f) ? 1.f : ((wv < 0.f) ? -1.f : 0.f);
            acc2 += s_sign[k] * ws_;
        }
        out[(size_t)row * N_OUT + o] = (acc2 * qs + bias[o]) * beta[o];
    }
}

// ---------------------------------------------------------------------------
extern "C" void kernel_launch(void* const* d_in, const int* in_sizes, int n_in,
                              void* d_out, int out_size, void* d_ws, size_t ws_size,
                              hipStream_t stream) {
    const float* input  = (const float*)d_in[0];
    const float* weight = (const float*)d_in[1];
    const float* bias   = (const float*)d_in[2];
    const float* gamma  = (const float*)d_in[3];
    const float* beta   = (const float*)d_in[4];
    float* out = (float*)d_out;

    const size_t aq_bytes = (size_t)M_ROWS * KB4;             // 8 MB
    const size_t wq_bytes = (size_t)N_OUT * KB4;              // 2 MB
    const size_t sc_bytes = (size_t)M_ROWS * sizeof(float);   // 32 KB

    if (ws_size >= aq_bytes + wq_bytes + sc_bytes) {
        uint8_t* aq    = (uint8_t*)d_ws;
        uint8_t* wqt   = (uint8_t*)d_ws + aq_bytes;
        float*   scale = (float*)((char*)d_ws + aq_bytes + wq_bytes);

        const int q_blocks = (M_ROWS + N_OUT) / 4;            // 2560 (4 waves/blk)
        quant_rows<<<q_blocks, 256, 0, stream>>>(
            input, weight, gamma, aq, wqt, scale);
        dim3 grid(M_ROWS / BM, N_OUT / BN);
        gemm_q<<<grid, 256, 0, stream>>>(aq, wqt, scale, bias, beta, out);
    } else {
        fallback_kernel<<<M_ROWS, 256, 0, stream>>>(input, weight, bias, gamma, beta, out);
    }
}